// Round 1
// baseline (28.053 us; speedup 1.0000x reference)
//
#include <hip/hip_runtime.h>

#define N_PATCH (32 * 112 * 112)

__global__ __launch_bounds__(256) void qfeat_kernel(const float* __restrict__ x,
                                                    const float* __restrict__ wts,
                                                    float* __restrict__ out) {
    // 8 gate matrices (2 layers x 4 wires), each 2x2 complex -> 8 floats:
    // [m00r, m00i, m01r, m01i, m10r, m10i, m11r, m11i]
    __shared__ float g[8][8];
    if (threadIdx.x < 8) {
        int gid = threadIdx.x;
        float phi   = wts[gid * 3 + 0];
        float theta = wts[gid * 3 + 1];
        float omega = wts[gid * 3 + 2];
        float st, ct; sincosf(0.5f * theta, &st, &ct);
        float sp, cp; sincosf(-0.5f * (phi + omega), &sp, &cp);   // ep = cp + i sp
        float sm, cm; sincosf(-0.5f * (phi - omega), &sm, &cm);   // em = cm + i sm
        g[gid][0] =  cp * ct;  g[gid][1] =  sp * ct;   // m00 = ep * c
        g[gid][2] = -cm * st;  g[gid][3] =  sm * st;   // m01 = -conj(em) * s
        g[gid][4] =  cm * st;  g[gid][5] =  sm * st;   // m10 = em * s
        g[gid][6] =  cp * ct;  g[gid][7] = -sp * ct;   // m11 = conj(ep) * c
    }
    __syncthreads();

    int pid = blockIdx.x * 256 + threadIdx.x;
    if (pid >= N_PATCH) return;

    int j = pid % 112;
    int t = pid / 112;
    int i = t % 112;
    int b = t / 112;

    // patch: wire0 = x[b,2i,2j], wire1 = x[b,2i,2j+1], wire2 = x[b,2i+1,2j], wire3 = x[b,2i+1,2j+1]
    const float2* r0 = reinterpret_cast<const float2*>(x + (((size_t)b * 224 + 2 * i) * 224 + 2 * j));
    const float2* r1 = reinterpret_cast<const float2*>(x + (((size_t)b * 224 + 2 * i + 1) * 224 + 2 * j));
    float2 top = *r0;
    float2 bot = *r1;
    float p[4] = {top.x, top.y, bot.x, bot.y};

    // Encoding: RY(a)RX(a)|0> with a = p*pi, half-angle = p*pi/2
    // v0 = c^2 + i s^2 ; v1 = s c - i c s
    float vr[4][2], vi[4][2];
#pragma unroll
    for (int w = 0; w < 4; ++w) {
        float s, c;
        sincosf(p[w] * 1.57079632679489662f, &s, &c);
        vr[w][0] = c * c;  vi[w][0] = s * s;
        vr[w][1] = s * c;  vi[w][1] = -c * s;
    }

    // Tensor product, staged: wire0 is MSB of the 4-bit state index.
    float t2r[4], t2i[4];
#pragma unroll
    for (int idx = 0; idx < 4; ++idx) {
        int b0 = idx >> 1, b1 = idx & 1;
        t2r[idx] = vr[0][b0] * vr[1][b1] - vi[0][b0] * vi[1][b1];
        t2i[idx] = vr[0][b0] * vi[1][b1] + vi[0][b0] * vr[1][b1];
    }
    float t3r[8], t3i[8];
#pragma unroll
    for (int idx = 0; idx < 8; ++idx) {
        int hi = idx >> 1, b2 = idx & 1;
        t3r[idx] = t2r[hi] * vr[2][b2] - t2i[hi] * vi[2][b2];
        t3i[idx] = t2r[hi] * vi[2][b2] + t2i[hi] * vr[2][b2];
    }
    float ar[16], ai[16];
#pragma unroll
    for (int idx = 0; idx < 16; ++idx) {
        int hi = idx >> 1, b3 = idx & 1;
        ar[idx] = t3r[hi] * vr[3][b3] - t3i[hi] * vi[3][b3];
        ai[idx] = t3r[hi] * vi[3][b3] + t3i[hi] * vr[3][b3];
    }

    // 2 StronglyEntanglingLayers: Rot on each wire, then ring of CNOTs (r=1, then r=2)
#pragma unroll
    for (int l = 0; l < 2; ++l) {
#pragma unroll
        for (int w = 0; w < 4; ++w) {
            const float* gm = g[l * 4 + w];
            float m00r = gm[0], m00i = gm[1], m01r = gm[2], m01i = gm[3];
            float m10r = gm[4], m10i = gm[5], m11r = gm[6], m11i = gm[7];
            const int mask = 8 >> w;
#pragma unroll
            for (int idx = 0; idx < 16; ++idx) {
                if (idx & mask) continue;
                const int k = idx | mask;
                float a0r = ar[idx], a0i = ai[idx];
                float a1r = ar[k],   a1i = ai[k];
                ar[idx] = m00r * a0r - m00i * a0i + m01r * a1r - m01i * a1i;
                ai[idx] = m00r * a0i + m00i * a0r + m01r * a1i + m01i * a1r;
                ar[k]   = m10r * a0r - m10i * a0i + m11r * a1r - m11i * a1i;
                ai[k]   = m10r * a0i + m10i * a0r + m11r * a1i + m11i * a1r;
            }
        }
        const int r = (l == 0) ? 1 : 2;
#pragma unroll
        for (int w = 0; w < 4; ++w) {
            const int mc = 8 >> w;
            const int mt = 8 >> ((w + r) & 3);
#pragma unroll
            for (int idx = 0; idx < 16; ++idx) {
                if ((idx & mc) && !(idx & mt)) {
                    const int k = idx | mt;
                    float tr = ar[idx]; ar[idx] = ar[k]; ar[k] = tr;
                    float ti = ai[idx]; ai[idx] = ai[k]; ai[k] = ti;
                }
            }
        }
    }

    // PauliZ expvals: wire w sign flips when bit (8>>w) set
    float o0 = 0.f, o1 = 0.f, o2 = 0.f, o3 = 0.f;
#pragma unroll
    for (int idx = 0; idx < 16; ++idx) {
        float pb = ar[idx] * ar[idx] + ai[idx] * ai[idx];
        o0 += (idx & 8) ? -pb : pb;
        o1 += (idx & 4) ? -pb : pb;
        o2 += (idx & 2) ? -pb : pb;
        o3 += (idx & 1) ? -pb : pb;
    }

    *reinterpret_cast<float4*>(out + (size_t)pid * 4) = make_float4(o0, o1, o2, o3);
}

extern "C" void kernel_launch(void* const* d_in, const int* in_sizes, int n_in,
                              void* d_out, int out_size, void* d_ws, size_t ws_size,
                              hipStream_t stream) {
    const float* x   = (const float*)d_in[0];
    const float* wts = (const float*)d_in[1];
    float* out       = (float*)d_out;
    const int nblocks = (N_PATCH + 255) / 256;
    qfeat_kernel<<<nblocks, 256, 0, stream>>>(x, wts, out);
}